// Round 4
// baseline (190.744 us; speedup 1.0000x reference)
//
#include <hip/hip_runtime.h>

// Cholesky-from-partial-correlations.
// Closed form per (batch b, row i):
//   out[b,i,j] = z_j * sqrt( prod_{k<j} (1 - z_k^2) )   for j < i
//   out[b,i,i] = 1,  out[b,i,j>i] = 0
// One 64-lane wave per FOUR consecutive rows: 4 independent scan chains
// interleaved for ILP (hides shuffle + HBM latency). Each lane owns 4
// consecutive elements per row; float4 stores (rows 1 KiB aligned).

#define SIZE 256
#define BATCH 512
#define M (SIZE * (SIZE - 1) / 2)   // 32640

__global__ __launch_bounds__(256) void chol_from_z_kernel(
    const float* __restrict__ vec, float* __restrict__ out) {
    const int lane = threadIdx.x & 63;
    const int wave = (blockIdx.x * blockDim.x + threadIdx.x) >> 6;  // 0 .. 32767
    const int b  = wave >> 6;           // batch index (512)
    const int i0 = (wave & 63) << 2;    // first of 4 consecutive rows
    const int j0 = lane << 2;           // this lane's first column

    // ---- phase 1: issue all 16 predicated loads (4 rows x 4 elems) ----
    float z[4][4];
    float t[4][4];
    #pragma unroll
    for (int r = 0; r < 4; ++r) {
        const int i = i0 + r;
        const int L = i;  // strictly-lower count
        const size_t row_off = (size_t)b * M + (size_t)((i * (i - 1)) >> 1);
        const float* __restrict__ s = vec + row_off;
        #pragma unroll
        for (int e = 0; e < 4; ++e) {
            z[r][e] = (j0 + e < L) ? s[j0 + e] : 0.f;
        }
    }

    // ---- phase 2: local products ----
    float local[4];
    #pragma unroll
    for (int r = 0; r < 4; ++r) {
        #pragma unroll
        for (int e = 0; e < 4; ++e) t[r][e] = 1.f - z[r][e] * z[r][e];
        local[r] = t[r][0] * t[r][1] * t[r][2] * t[r][3];
    }

    // ---- phase 3: four independent wave scans, interleaved ----
    float p[4];
    #pragma unroll
    for (int r = 0; r < 4; ++r) p[r] = local[r];
    #pragma unroll
    for (int d = 1; d < 64; d <<= 1) {
        #pragma unroll
        for (int r = 0; r < 4; ++r) {
            float v = __shfl_up(p[r], d, 64);
            if (lane >= d) p[r] *= v;
        }
    }

    // ---- phase 4: emit + store ----
    float* __restrict__ dst = out + (((size_t)b << 8) + (size_t)i0) * SIZE + j0;
    #pragma unroll
    for (int r = 0; r < 4; ++r) {
        const int i = i0 + r;
        const int L = i;
        float run = __shfl_up(p[r], 1, 64);
        if (lane == 0) run = 1.f;
        float4 o;
        o.x = (j0     < L) ? z[r][0] * sqrtf(run) : ((j0     == i) ? 1.f : 0.f); run *= t[r][0];
        o.y = (j0 + 1 < L) ? z[r][1] * sqrtf(run) : ((j0 + 1 == i) ? 1.f : 0.f); run *= t[r][1];
        o.z = (j0 + 2 < L) ? z[r][2] * sqrtf(run) : ((j0 + 2 == i) ? 1.f : 0.f); run *= t[r][2];
        o.w = (j0 + 3 < L) ? z[r][3] * sqrtf(run) : ((j0 + 3 == i) ? 1.f : 0.f);
        *(float4*)(dst + (size_t)r * SIZE) = o;
    }
}

extern "C" void kernel_launch(void* const* d_in, const int* in_sizes, int n_in,
                              void* d_out, int out_size, void* d_ws, size_t ws_size,
                              hipStream_t stream) {
    const float* vec = (const float*)d_in[0];
    float* out = (float*)d_out;
    const int n_waves = BATCH * SIZE / 4;       // 32768 waves, 4 rows each
    const int blocks = n_waves / 4;             // 4 waves (256 thr) per block
    chol_from_z_kernel<<<blocks, 256, 0, stream>>>(vec, out);
}

// Round 5
// 180.807 us; speedup vs baseline: 1.0550x; 1.0550x over previous
//
#include <hip/hip_runtime.h>

// Cholesky-from-partial-correlations.
// Closed form per (batch b, row i):
//   out[b,i,j] = z_j * sqrt( prod_{k<j} (1 - z_k^2) )   for j < i
//   out[b,i,i] = 1,  out[b,i,j>i] = 0
// One 64-lane wave per row (TLP > ILP here: 131072 waves).
// Wave-wide prefix product via all-VALU DPP scan:
//   row_shr:1/2/4/8 within 16-lane rows, then row_bcast:15 (rows 1,3),
//   row_bcast:31 (rows 2,3). Identity fill (1.0f) via update_dpp's `old`.
// Only the final exclusive shift uses the DS path (__shfl_up by 1).

#define SIZE 256
#define BATCH 512
#define M (SIZE * (SIZE - 1) / 2)   // 32640

// p *= dpp_shifted(p), masked lanes / invalid sources contribute 1.0f (identity)
template <int CTRL, int ROW_MASK>
__device__ __forceinline__ float scan_mul(float p) {
    int shifted = __builtin_amdgcn_update_dpp(
        __builtin_bit_cast(int, 1.0f),       // old: identity for unwritten lanes
        __builtin_bit_cast(int, p),
        CTRL, ROW_MASK, 0xF, false);         // bound_ctrl=false -> keep old
    return p * __builtin_bit_cast(float, shifted);
}

__global__ __launch_bounds__(256) void chol_from_z_kernel(
    const float* __restrict__ vec, float* __restrict__ out) {
    const int lane = threadIdx.x & 63;
    const int wave = (blockIdx.x * blockDim.x + threadIdx.x) >> 6;  // 0 .. BATCH*SIZE-1
    const int b = wave >> 8;      // batch index
    const int i = wave & 255;     // row index

    const size_t row_off = (size_t)b * M + (size_t)((i * (i - 1)) >> 1);
    const float* __restrict__ s = vec + row_off;
    float* __restrict__ dst = out + (((size_t)b << 8) + (size_t)i) * SIZE;

    const int L = i;              // strictly-lower entry count in this row
    const int j0 = lane << 2;     // this lane's first column

    // predicated loads; z=0 outside row -> t=1 (identity)
    const float z0 = (j0     < L) ? s[j0]     : 0.f;
    const float z1 = (j0 + 1 < L) ? s[j0 + 1] : 0.f;
    const float z2 = (j0 + 2 < L) ? s[j0 + 2] : 0.f;
    const float z3 = (j0 + 3 < L) ? s[j0 + 3] : 0.f;

    const float t0 = 1.f - z0 * z0;
    const float t1 = 1.f - z1 * z1;
    const float t2 = 1.f - z2 * z2;
    const float t3 = 1.f - z3 * z3;

    float p = (t0 * t1) * (t2 * t3);

    // wave64 inclusive prefix product — 6 VALU DPP steps
    p = scan_mul<0x111, 0xF>(p);  // row_shr:1
    p = scan_mul<0x112, 0xF>(p);  // row_shr:2
    p = scan_mul<0x114, 0xF>(p);  // row_shr:4
    p = scan_mul<0x118, 0xF>(p);  // row_shr:8
    p = scan_mul<0x142, 0xA>(p);  // row_bcast:15 -> rows 1,3
    p = scan_mul<0x143, 0xC>(p);  // row_bcast:31 -> rows 2,3

    // exclusive prefix entering this lane's 4-element segment
    float run = __shfl_up(p, 1, 64);
    if (lane == 0) run = 1.f;

    float4 o;
    o.x = (j0     < L) ? z0 * sqrtf(run) : ((j0     == i) ? 1.f : 0.f); run *= t0;
    o.y = (j0 + 1 < L) ? z1 * sqrtf(run) : ((j0 + 1 == i) ? 1.f : 0.f); run *= t1;
    o.z = (j0 + 2 < L) ? z2 * sqrtf(run) : ((j0 + 2 == i) ? 1.f : 0.f); run *= t2;
    o.w = (j0 + 3 < L) ? z3 * sqrtf(run) : ((j0 + 3 == i) ? 1.f : 0.f);

    *(float4*)(dst + j0) = o;   // rows are 1 KiB aligned; j0 is 16B aligned
}

extern "C" void kernel_launch(void* const* d_in, const int* in_sizes, int n_in,
                              void* d_out, int out_size, void* d_ws, size_t ws_size,
                              hipStream_t stream) {
    const float* vec = (const float*)d_in[0];
    float* out = (float*)d_out;
    const int n_waves = BATCH * SIZE;           // 131072 rows, 1 wave each
    const int blocks = n_waves / 4;             // 4 waves (256 thr) per block
    chol_from_z_kernel<<<blocks, 256, 0, stream>>>(vec, out);
}

// Round 6
// 176.160 us; speedup vs baseline: 1.0828x; 1.0264x over previous
//
#include <hip/hip_runtime.h>

// Cholesky-from-partial-correlations.
//   out[b,i,j] = z_j * sqrt( prod_{k<j} (1 - z_k^2) )  for j < i;  1 on diag; 0 above.
// One wave per row; wave-wide prefix product via all-VALU DPP scan.
// VALU-issue-bound -> row-length-specialized paths (C elems/lane, C in {1,2,4}),
// scalarized wave-uniform addressing, unconditional loads + value masks,
// DPP wave_shr:1 exclusive shift.

#define SIZE 256
#define BATCH 512
#define M (SIZE * (SIZE - 1) / 2)   // 32640
#define TOTAL (BATCH * M)           // 16711680

// p *= dpp_shifted(p); invalid lanes contribute 1.0f (identity) via `old`
template <int CTRL, int ROW_MASK>
__device__ __forceinline__ float scan_mul(float p) {
    int sh = __builtin_amdgcn_update_dpp(
        __builtin_bit_cast(int, 1.0f),
        __builtin_bit_cast(int, p),
        CTRL, ROW_MASK, 0xF, false);
    return p * __builtin_bit_cast(float, sh);
}

// whole-wave shift right by 1; lane 0 gets 1.0f (exclusive-scan carry-in)
__device__ __forceinline__ float excl_shift_one(float p) {
    int r = __builtin_amdgcn_update_dpp(
        __builtin_bit_cast(int, 1.0f),
        __builtin_bit_cast(int, p),
        0x138 /* wave_shr:1 */, 0xF, 0xF, false);
    return __builtin_bit_cast(float, r);
}

template <int C>
__device__ __forceinline__ void do_row(const float* __restrict__ s,
                                       float* __restrict__ dst,
                                       const int i, const int lane,
                                       const int maxidx) {
    const int j0 = lane * C;

    float z[C], t[C];
    #pragma unroll
    for (int e = 0; e < C; ++e) {
        int idx = j0 + e;
        if (C == 4 && e == 3) idx = (idx < maxidx) ? idx : maxidx;  // only possible OOB elem
        const float raw = s[idx];
        z[e] = (j0 < i - e) ? raw : 0.f;      // zero outside strictly-lower region
        t[e] = 1.f - z[e] * z[e];
    }

    float local = t[0];
    #pragma unroll
    for (int e = 1; e < C; ++e) local *= t[e];

    // wave64 inclusive prefix product — 6 VALU DPP steps
    float p = local;
    p = scan_mul<0x111, 0xF>(p);  // row_shr:1
    p = scan_mul<0x112, 0xF>(p);  // row_shr:2
    p = scan_mul<0x114, 0xF>(p);  // row_shr:4
    p = scan_mul<0x118, 0xF>(p);  // row_shr:8
    p = scan_mul<0x142, 0xA>(p);  // row_bcast:15 -> rows 1,3
    p = scan_mul<0x143, 0xC>(p);  // row_bcast:31 -> rows 2,3

    float run = excl_shift_one(p);

    float o[C];
    #pragma unroll
    for (int e = 0; e < C; ++e) {
        const float v = z[e] * sqrtf(run);        // 0 automatically above diagonal
        o[e] = (j0 == i - e) ? 1.f : v;           // diagonal fixup
        run *= t[e];
    }

    if (C == 4) {
        *(float4*)(dst + j0) = make_float4(o[0], o[1], o[2], o[3]);
    } else if (C == 2) {
        *(float2*)(dst + j0) = make_float2(o[0], o[1]);            // cols 0..127
        *(float2*)(dst + 128 + j0) = make_float2(0.f, 0.f);        // cols 128..255 zero
    } else {
        dst[j0] = o[0];                                            // cols 0..63
        dst[64 + j0] = 0.f;                                        // zeros, coalesced
        dst[128 + j0] = 0.f;
        dst[192 + j0] = 0.f;
    }
}

__global__ __launch_bounds__(256) void chol_from_z_kernel(
    const float* __restrict__ vec, float* __restrict__ out) {
    const int lane = threadIdx.x & 63;
    // wave-uniform scalars (force SALU)
    const int wib = __builtin_amdgcn_readfirstlane((int)threadIdx.x >> 6);
    const int wave = (int)blockIdx.x * 4 + wib;   // 0 .. BATCH*SIZE-1
    const int b = wave >> 8;
    const int i = wave & 255;

    const int row_off = b * M + ((i * (i - 1)) >> 1);
    const float* __restrict__ s = vec + row_off;
    float* __restrict__ dst = out + ((size_t)wave << 8);
    const int maxidx = (TOTAL - 1) - row_off;     // clamp for the single possible OOB read

    if (i < 64)        do_row<1>(s, dst, i, lane, maxidx);
    else if (i < 128)  do_row<2>(s, dst, i, lane, maxidx);
    else               do_row<4>(s, dst, i, lane, maxidx);
}

extern "C" void kernel_launch(void* const* d_in, const int* in_sizes, int n_in,
                              void* d_out, int out_size, void* d_ws, size_t ws_size,
                              hipStream_t stream) {
    const float* vec = (const float*)d_in[0];
    float* out = (float*)d_out;
    const int n_waves = BATCH * SIZE;           // 131072 rows, 1 wave each
    const int blocks = n_waves / 4;             // 4 waves (256 thr) per block
    chol_from_z_kernel<<<blocks, 256, 0, stream>>>(vec, out);
}

// Round 7
// 174.824 us; speedup vs baseline: 1.0911x; 1.0076x over previous
//
#include <hip/hip_runtime.h>

// Cholesky-from-partial-correlations.
//   out[b,i,j] = z_j * sqrt( prod_{k<j} (1 - z_k^2) )  for j < i;  1 on diag; 0 above.
// One wave per row (131072 waves). Memory-path minimized: exactly ONE
// (possibly unaligned) float4 load and ONE aligned float4 store per lane.
// Wave prefix product via all-VALU DPP scan; short rows skip bcast steps
// (wave-uniform branches). Raw v_sqrt_f32 (error budget 2e-2 >> 1 ulp).

#define SIZE 256
#define BATCH 512
#define M (SIZE * (SIZE - 1) / 2)   // 32640
#define TOTAL (BATCH * M)           // 16711680

// 4-byte-aligned float4 — lets the backend emit an unaligned dwordx4
typedef float f4u __attribute__((ext_vector_type(4), aligned(4)));

// p *= dpp_shifted(p); invalid lanes contribute 1.0f (identity) via `old`
template <int CTRL, int ROW_MASK>
__device__ __forceinline__ float scan_mul(float p) {
    int sh = __builtin_amdgcn_update_dpp(
        __builtin_bit_cast(int, 1.0f),
        __builtin_bit_cast(int, p),
        CTRL, ROW_MASK, 0xF, false);
    return p * __builtin_bit_cast(float, sh);
}

// whole-wave shift right by 1; lane 0 gets 1.0f (exclusive-scan carry-in)
__device__ __forceinline__ float excl_shift_one(float p) {
    int r = __builtin_amdgcn_update_dpp(
        __builtin_bit_cast(int, 1.0f),
        __builtin_bit_cast(int, p),
        0x138 /* wave_shr:1 */, 0xF, 0xF, false);
    return __builtin_bit_cast(float, r);
}

__global__ __launch_bounds__(256) void chol_from_z_kernel(
    const float* __restrict__ vec, float* __restrict__ out) {
    const int lane = threadIdx.x & 63;
    const int wib = __builtin_amdgcn_readfirstlane((int)threadIdx.x >> 6);
    const int wave = (int)blockIdx.x * 4 + wib;   // 0 .. BATCH*SIZE-1
    const int b = wave >> 8;                      // batch
    const int i = wave & 255;                     // row
    const int row_off = b * M + ((i * (i - 1)) >> 1);
    const float* __restrict__ s = vec + row_off;
    float* __restrict__ dst = out + ((size_t)wave << 8);
    const int j0 = lane << 2;

    // ---- single vector load per lane (garbage past row end is masked) ----
    const int maxidx = (TOTAL - 1) - row_off;     // last valid index in s[]
    f4u zv;
    if (j0 + 3 <= maxidx) {                       // all lanes except lane 63 of the
        zv = *(const f4u*)(s + j0);               // globally-last row
    } else {
        zv.x = s[j0]; zv.y = s[j0 + 1]; zv.z = s[j0 + 2]; zv.w = 0.f;
    }

    // mask to strictly-lower region
    const float z0 = (j0     < i) ? zv.x : 0.f;
    const float z1 = (j0 + 1 < i) ? zv.y : 0.f;
    const float z2 = (j0 + 2 < i) ? zv.z : 0.f;
    const float z3 = (j0 + 3 < i) ? zv.w : 0.f;

    const float t0 = 1.f - z0 * z0;
    const float t1 = 1.f - z1 * z1;
    const float t2 = 1.f - z2 * z2;
    const float t3 = 1.f - z3 * z3;

    float p = (t0 * t1) * (t2 * t3);

    // wave64 inclusive prefix product — up to 6 VALU DPP steps;
    // rows with diagonal inside the first 16/32 lanes skip bcast steps
    p = scan_mul<0x111, 0xF>(p);                  // row_shr:1
    p = scan_mul<0x112, 0xF>(p);                  // row_shr:2
    p = scan_mul<0x114, 0xF>(p);                  // row_shr:4
    p = scan_mul<0x118, 0xF>(p);                  // row_shr:8
    if (i >= 64)  p = scan_mul<0x142, 0xA>(p);    // row_bcast:15 -> rows 1,3
    if (i >= 128) p = scan_mul<0x143, 0xC>(p);    // row_bcast:31 -> rows 2,3

    float run = excl_shift_one(p);

    f4u o;
    o.x = (j0     == i) ? 1.f : z0 * __builtin_amdgcn_sqrtf(run); run *= t0;
    o.y = (j0 + 1 == i) ? 1.f : z1 * __builtin_amdgcn_sqrtf(run); run *= t1;
    o.z = (j0 + 2 == i) ? 1.f : z2 * __builtin_amdgcn_sqrtf(run); run *= t2;
    o.w = (j0 + 3 == i) ? 1.f : z3 * __builtin_amdgcn_sqrtf(run);

    *(f4u*)(dst + j0) = o;        // dst 1 KiB-aligned, j0*4 is 16B multiple
}

extern "C" void kernel_launch(void* const* d_in, const int* in_sizes, int n_in,
                              void* d_out, int out_size, void* d_ws, size_t ws_size,
                              hipStream_t stream) {
    const float* vec = (const float*)d_in[0];
    float* out = (float*)d_out;
    const int n_waves = BATCH * SIZE;           // 131072 rows, 1 wave each
    const int blocks = n_waves / 4;             // 4 waves (256 thr) per block
    chol_from_z_kernel<<<blocks, 256, 0, stream>>>(vec, out);
}